// Round 1
// baseline (757.734 us; speedup 1.0000x reference)
//
#include <hip/hip_runtime.h>

static __device__ __forceinline__ float frelu(float v){ return v > 0.f ? v : 0.f; }

// ---------------------------------------------------------------------------
// Detect whether edge_index buffer is int64 (odd 32-bit words all zero) or int32.
// flag = 1 -> int64, 0 -> int32. Values are node ids < 100000, so int64 high
// words are always 0; for int32 data the odd positions are real indices
// (P(all 512 samples == 0) ~ 0).
__global__ void detect_kernel(const unsigned int* __restrict__ e, int* __restrict__ flag){
    __shared__ int odd_nz;
    if (threadIdx.x == 0) odd_nz = 0;
    __syncthreads();
    int local = 0;
    for (int i = threadIdx.x; i < 512; i += blockDim.x){
        if (e[2*i + 1] != 0u) local = 1;
    }
    if (local) atomicOr(&odd_nz, 1);
    __syncthreads();
    if (threadIdx.x == 0) *flag = (odd_nz == 0) ? 1 : 0;
}

// in-degree count (edges only; self-loop handled analytically later)
__global__ void count_kernel(const void* __restrict__ eidx, const int* __restrict__ flag,
                             int* __restrict__ deg, int E){
    int i = blockIdx.x * blockDim.x + threadIdx.x;
    if (i >= E) return;
    int dst;
    if (*flag) dst = (int)((const long long*)eidx)[(long long)E + i];
    else       dst = ((const int*)eidx)[E + i];
    atomicAdd(&deg[dst], 1);
}

__global__ void dis_kernel(const int* __restrict__ deg, float* __restrict__ dis, int N){
    int i = blockIdx.x * blockDim.x + threadIdx.x;
    if (i < N) dis[i] = rsqrtf((float)(deg[i] + 1));   // +1 = self loop
}

// single-block exclusive scan of deg[N] -> offsets[N+1]
__global__ void scan_kernel(const int* __restrict__ deg, int* __restrict__ offsets, int N){
    __shared__ int sums[1024];
    int tid = threadIdx.x;
    int chunk = (N + 1023) / 1024;
    int start = tid * chunk;
    int end   = min(start + chunk, N);
    int s = 0;
    for (int i = start; i < end; ++i) s += deg[i];
    sums[tid] = s;
    __syncthreads();
    for (int off = 1; off < 1024; off <<= 1){
        int t = (tid >= off) ? sums[tid - off] : 0;
        __syncthreads();
        sums[tid] += t;
        __syncthreads();
    }
    int run = sums[tid] - s;          // exclusive prefix for this chunk
    for (int i = start; i < end; ++i){ offsets[i] = run; run += deg[i]; }
    if (tid == 1023) offsets[N] = sums[1023];
}

// counting-sort scatter: csr[pos] = src for each edge, bucketed by dst
__global__ void scatter_kernel(const void* __restrict__ eidx, const int* __restrict__ flag,
                               const int* __restrict__ offsets, int* __restrict__ cursor,
                               int* __restrict__ csr, int E){
    int i = blockIdx.x * blockDim.x + threadIdx.x;
    if (i >= E) return;
    int src, dst;
    if (*flag){
        const long long* p = (const long long*)eidx;
        src = (int)p[i];
        dst = (int)p[(long long)E + i];
    } else {
        const int* p = (const int*)eidx;
        src = p[i];
        dst = p[E + i];
    }
    int pos = offsets[dst] + atomicAdd(&cursor[dst], 1);
    csr[pos] = src;
}

// h1s[i][c] = (x[i,:] @ W1[:,c]) * dis[i]    x:[N,256] W1:[256,32]
// 8 lane-groups of 32 per block; each group computes 8 rows, W1 chunk in regs.
__global__ __launch_bounds__(256) void gemm1_kernel(const float* __restrict__ x,
        const float* __restrict__ W1, const float* __restrict__ dis,
        float* __restrict__ h1s, int N){
    int lane = threadIdx.x & 31;
    int grp  = threadIdx.x >> 5;
    int row0 = (blockIdx.x * 8 + grp) * 8;
    float acc[8];
#pragma unroll
    for (int r = 0; r < 8; ++r) acc[r] = 0.f;
    for (int c = 0; c < 4; ++c){
        int k0 = c * 64;
        float w[64];
#pragma unroll
        for (int kk = 0; kk < 64; ++kk) w[kk] = W1[(k0 + kk) * 32 + lane];
#pragma unroll
        for (int r = 0; r < 8; ++r){
            int row = row0 + r;
            if (row < N){
                const float4* xr = (const float4*)(x + row * 256 + k0);
#pragma unroll
                for (int q = 0; q < 16; ++q){
                    float4 xv = xr[q];
                    acc[r] += xv.x * w[q*4+0] + xv.y * w[q*4+1]
                            + xv.z * w[q*4+2] + xv.w * w[q*4+3];
                }
            }
        }
    }
#pragma unroll
    for (int r = 0; r < 8; ++r){
        int row = row0 + r;
        if (row < N) h1s[row * 32 + lane] = acc[r] * dis[row];
    }
}

// aggregation over CSR: out_i = f( (Σ_{j∈N(i)} hs_j + hs_i) * dis_i )
// 32 lanes per node; lane = (edge-slot q = lane>>3, feature-quad fq = lane&7).
// One 64-lane load instruction gathers 8 edges' float4 fragments.
__global__ __launch_bounds__(256) void agg_kernel(
        const float* __restrict__ hs, const int* __restrict__ offsets,
        const int* __restrict__ csr, const float* __restrict__ dis,
        const float* __restrict__ bias, float* __restrict__ outb,
        int N, int mode){   // mode 1: relu(v+b)*dis ; mode 0: v
    int g    = (blockIdx.x * blockDim.x + threadIdx.x) >> 5;
    int lane = threadIdx.x & 31;
    if (g >= N) return;
    int q  = lane >> 3;
    int fq = lane & 7;
    int beg = offsets[g], end = offsets[g + 1];
    float4 acc = make_float4(0.f, 0.f, 0.f, 0.f);
    for (int k = beg; k < end; k += 32){
        int idx = (k + lane < end) ? csr[k + lane] : -1;
        int nb = end - k; if (nb > 32) nb = 32;
        for (int j = 0; j < nb; j += 4){
            int s = __shfl(idx, j + q, 32);
            if (s >= 0){
                float4 v = ((const float4*)hs)[s * 8 + fq];
                acc.x += v.x; acc.y += v.y; acc.z += v.z; acc.w += v.w;
            }
        }
    }
    acc.x += __shfl_xor(acc.x, 8, 32);  acc.y += __shfl_xor(acc.y, 8, 32);
    acc.z += __shfl_xor(acc.z, 8, 32);  acc.w += __shfl_xor(acc.w, 8, 32);
    acc.x += __shfl_xor(acc.x, 16, 32); acc.y += __shfl_xor(acc.y, 16, 32);
    acc.z += __shfl_xor(acc.z, 16, 32); acc.w += __shfl_xor(acc.w, 16, 32);
    if (q == 0){
        float4 self = ((const float4*)hs)[g * 8 + fq];
        float d = dis[g];
        float4 r;
        r.x = (acc.x + self.x) * d; r.y = (acc.y + self.y) * d;
        r.z = (acc.z + self.z) * d; r.w = (acc.w + self.w) * d;
        if (mode == 1){
            float4 b = ((const float4*)bias)[fq];
            r.x = frelu(r.x + b.x) * d; r.y = frelu(r.y + b.y) * d;
            r.z = frelu(r.z + b.z) * d; r.w = frelu(r.w + b.w) * d;
        }
        ((float4*)outb)[g * 8 + fq] = r;
    }
}

// out[i][c] = a2[i,:] @ W2[:,c] + b2[c]    a2:[N,32] W2:[32,128]
__global__ __launch_bounds__(128) void gemm2_kernel(const float* __restrict__ a2,
        const float* __restrict__ W2, const float* __restrict__ b2,
        float* __restrict__ out, int N){
    int c = threadIdx.x;
    int base = blockIdx.x * 32;
    float w[32];
#pragma unroll
    for (int k = 0; k < 32; ++k) w[k] = W2[k * 128 + c];
    float bias = b2[c];
    for (int r = 0; r < 32; ++r){
        int row = base + r;
        if (row >= N) break;
        const float4* ar = (const float4*)(a2 + row * 32);
        float acc = bias;
#pragma unroll
        for (int p = 0; p < 8; ++p){
            float4 av = ar[p];
            acc += av.x * w[p*4+0] + av.y * w[p*4+1]
                 + av.z * w[p*4+2] + av.w * w[p*4+3];
        }
        out[row * 128 + c] = acc;
    }
}

extern "C" void kernel_launch(void* const* d_in, const int* in_sizes, int n_in,
                              void* d_out, int out_size, void* d_ws, size_t ws_size,
                              hipStream_t stream){
    const float* x  = (const float*)d_in[0];
    const void*  ei = d_in[1];
    const float* W1 = (const float*)d_in[2];
    const float* b1 = (const float*)d_in[3];
    const float* W2 = (const float*)d_in[4];
    const float* b2 = (const float*)d_in[5];
    float* out = (float*)d_out;

    const int N = in_sizes[0] / 256;   // 100000
    const int E = in_sizes[1] / 2;     // 3200000

    char* ws = (char*)d_ws;
    size_t off = 0;
    auto alloc = [&](size_t bytes) -> char* {
        char* p = ws + off;
        off = (off + bytes + 255) & ~(size_t)255;
        return p;
    };
    int*   flag    = (int*)  alloc(4);
    int*   deg     = (int*)  alloc((size_t)N * 4);
    int*   offsets = (int*)  alloc((size_t)(N + 1) * 4);
    int*   cursor  = (int*)  alloc((size_t)N * 4);
    float* dis     = (float*)alloc((size_t)N * 4);
    int*   csr     = (int*)  alloc((size_t)E * 4);
    float* h1s     = (float*)alloc((size_t)N * 32 * 4);
    float* h2s     = (float*)alloc((size_t)N * 32 * 4);
    float* a2      = h1s;   // h1s dead after first aggregation

    hipMemsetAsync(deg,    0, (size_t)N * 4, stream);
    hipMemsetAsync(cursor, 0, (size_t)N * 4, stream);

    detect_kernel <<<1, 256, 0, stream>>>((const unsigned int*)ei, flag);
    count_kernel  <<<(E + 255) / 256, 256, 0, stream>>>(ei, flag, deg, E);
    dis_kernel    <<<(N + 255) / 256, 256, 0, stream>>>(deg, dis, N);
    scan_kernel   <<<1, 1024, 0, stream>>>(deg, offsets, N);
    scatter_kernel<<<(E + 255) / 256, 256, 0, stream>>>(ei, flag, offsets, cursor, csr, E);

    gemm1_kernel  <<<(N + 63) / 64, 256, 0, stream>>>(x, W1, dis, h1s, N);
    agg_kernel    <<<(N + 7) / 8, 256, 0, stream>>>(h1s, offsets, csr, dis, b1, h2s, N, 1);
    agg_kernel    <<<(N + 7) / 8, 256, 0, stream>>>(h2s, offsets, csr, dis, b2, a2, N, 0);
    gemm2_kernel  <<<(N + 31) / 32, 128, 0, stream>>>(a2, W2, b2, out, N);
}